// Round 2
// baseline (18728.140 us; speedup 1.0000x reference)
//
#include <hip/hip_runtime.h>
#include <hip/hip_bf16.h>

// LSTM T=2048, B=64, I=256, H=512 — persistent single-kernel scan, f32 I/O.
// Internal compute: bf16 MFMA (16x16x32) + f32 cell chain (threshold permits bf16).
// Grid barrier per step: monotone counter in d_ws, agent-scope atomics.
// 128 blocks x 128 threads: block = (mg = batch rows 16mg..+16, ng = h-cols 16ng..+16).
// Wave 0 -> f,i gate tiles; wave 1 -> c~,o tiles. Weights persist in VGPRs (192/wave).
// h feedback: bf16 ping-pong in d_ws (2 x B*H), so timed replays never depend on d_out's
// poisoned contents; d_out receives f32 h / h_last / c_last.

#define T_STEPS 2048
#define BATCH   64
#define IN_F    256
#define HID     512
#define KTOT    768          // H + I, concat order (h, x)
#define BHSZ    (BATCH*HID)  // 32768
#define NBLK    128

typedef __attribute__((ext_vector_type(8))) short  short8;  // 8 bf16 = 4 VGPRs
typedef __attribute__((ext_vector_type(4))) float  f32x4;

__device__ __forceinline__ f32x4 mfma16(short8 a, short8 b, f32x4 c) {
    return __builtin_amdgcn_mfma_f32_16x16x32_bf16(a, b, c, 0, 0, 0);
}
__device__ __forceinline__ short bf16bits(float f) {
    return (short)__builtin_bit_cast(unsigned short, __float2bfloat16(f));
}
__device__ __forceinline__ short8 cvt8(const float* __restrict__ p) {
    f32x4 a = *(const f32x4*)p;
    f32x4 b = *(const f32x4*)(p + 4);
    short8 r;
    r[0] = bf16bits(a[0]); r[1] = bf16bits(a[1]); r[2] = bf16bits(a[2]); r[3] = bf16bits(a[3]);
    r[4] = bf16bits(b[0]); r[5] = bf16bits(b[1]); r[6] = bf16bits(b[2]); r[7] = bf16bits(b[3]);
    return r;
}
__device__ __forceinline__ float sigf(float x)      { return 1.f / (1.f + __expf(-x)); }
__device__ __forceinline__ float tanh_fast(float x) { return 2.f / (1.f + __expf(-2.f * x)) - 1.f; }

__global__ void __launch_bounds__(128, 1)
lstm_persistent(const float* __restrict__ x,
                const float* __restrict__ Wf, const float* __restrict__ bfv,
                const float* __restrict__ Wi, const float* __restrict__ biv,
                const float* __restrict__ Wc, const float* __restrict__ bcv,
                const float* __restrict__ Wo, const float* __restrict__ bov,
                float* __restrict__ out, unsigned* cnt, short* hping)
{
    const int tid  = threadIdx.x;
    const int wv   = tid >> 6;        // wave 0: f,i   wave 1: c~,o
    const int lane = tid & 63;
    const int bn   = lane & 15;       // A-row / B-col / C-col within the 16-tile
    const int quad = lane >> 4;
    const int mg   = blockIdx.x & 3;  // batch-row group
    const int ng   = blockIdx.x >> 2; // h-col group (0..31)
    const int hbase = ng << 4;
    const int m0    = mg << 4;

    // ---- preload B fragments (weights) f32 -> bf16, persist in VGPRs all 2048 steps ----
    // B[k][n] = W[row = hbase+n][k]; lane n=bn reads 8 contiguous k at k = kt*32 + quad*8.
    short8 Ba[24], Bb[24];
    {
        const float* ra = (wv ? Wc : Wf) + (size_t)(hbase + bn) * KTOT + quad * 8;
        const float* rb = (wv ? Wo : Wi) + (size_t)(hbase + bn) * KTOT + quad * 8;
        #pragma unroll
        for (int kt = 0; kt < 24; ++kt) {
            Ba[kt] = cvt8(ra + kt * 32);
            Bb[kt] = cvt8(rb + kt * 32);
        }
    }

    // ---- epilogue cell ownership: thread -> (rows er, er+8) x (col ec); c in fp32 regs ----
    const int ec = tid & 15;
    const int er = tid >> 4;          // 0..7
    const float vbf = bfv[hbase + ec];
    const float vbi = biv[hbase + ec];
    const float vbc = bcv[hbase + ec];
    const float vbo = bov[hbase + ec];
    float c0 = 0.f, c1 = 0.f;

    __shared__ float glds[4][16][17];  // gate preacts f,i,c~,o (padded stride 17)

    #pragma unroll 1
    for (int t = 0; t < T_STEPS; ++t) {
        f32x4 aA = {0.f,0.f,0.f,0.f}, aA2 = aA, aB = aA, aB2 = aA;

        // x-part first: independent of h_{t-1}, overlaps the barrier spin below.
        {
            const float* xr = x + ((size_t)t * BATCH + m0 + bn) * IN_F + quad * 8;
            #pragma unroll
            for (int kt = 0; kt < 8; ++kt) {
                short8 av = cvt8(xr + kt * 32);
                if (kt & 1) { aA2 = mfma16(av, Ba[16 + kt], aA2); aB2 = mfma16(av, Bb[16 + kt], aB2); }
                else        { aA  = mfma16(av, Ba[16 + kt], aA ); aB  = mfma16(av, Bb[16 + kt], aB ); }
            }
        }

        if (t > 0) {
            // wait until all NBLK blocks published h_{t-1}
            if (tid == 0) {
                const unsigned tgt = (unsigned)NBLK * (unsigned)t;
                while (__hip_atomic_load(cnt, __ATOMIC_RELAXED, __HIP_MEMORY_SCOPE_AGENT) < tgt)
                    __builtin_amdgcn_s_sleep(1);
                __builtin_amdgcn_fence(__ATOMIC_ACQUIRE, "agent");  // invalidate stale cache
            }
            __syncthreads();
            const short* hr = hping + (size_t)((t - 1) & 1) * BHSZ + (m0 + bn) * HID + quad * 8;
            #pragma unroll
            for (int kt = 0; kt < 16; ++kt) {
                short8 av = *(const short8*)(hr + kt * 32);
                if (kt & 1) { aA2 = mfma16(av, Ba[kt], aA2); aB2 = mfma16(av, Bb[kt], aB2); }
                else        { aA  = mfma16(av, Ba[kt], aA ); aB  = mfma16(av, Bb[kt], aB ); }
            }
        }
        aA += aA2; aB += aB2;

        // C/D layout (verified m89): col = lane&15, row = quad*4 + reg
        #pragma unroll
        for (int r = 0; r < 4; ++r) {
            glds[wv * 2 + 0][quad * 4 + r][bn] = aA[r];
            glds[wv * 2 + 1][quad * 4 + r][bn] = aB[r];
        }
        __syncthreads();

        // elementwise LSTM cell, fp32; two (row, col) cells per thread
        const float f0 = sigf(glds[0][er][ec] + vbf);
        const float i0 = sigf(glds[1][er][ec] + vbi);
        const float g0 = tanh_fast(glds[2][er][ec] + vbc);
        const float o0 = sigf(glds[3][er][ec] + vbo);
        c0 = f0 * c0 + i0 * g0;
        const float h0 = o0 * tanh_fast(c0);

        const float f1 = sigf(glds[0][er + 8][ec] + vbf);
        const float i1 = sigf(glds[1][er + 8][ec] + vbi);
        const float g1 = tanh_fast(glds[2][er + 8][ec] + vbc);
        const float o1 = sigf(glds[3][er + 8][ec] + vbo);
        c1 = f1 * c1 + i1 * g1;
        const float h1 = o1 * tanh_fast(c1);

        // f32 h to d_out; bf16 h to ws ping-pong for next step's MFMA A-operand
        const size_t ob = (size_t)t * BHSZ + (size_t)(m0 + er) * HID + hbase + ec;
        out[ob]           = h0;
        out[ob + 8 * HID] = h1;
        short* hw = hping + (size_t)(t & 1) * BHSZ + (size_t)(m0 + er) * HID + hbase + ec;
        hw[0]       = bf16bits(h0);
        hw[8 * HID] = bf16bits(h1);
        if (t == T_STEPS - 1) {  // h_last
            const size_t ol = (size_t)T_STEPS * BHSZ + (size_t)(m0 + er) * HID + hbase + ec;
            out[ol]           = h0;
            out[ol + 8 * HID] = h1;
        }

        __syncthreads();  // drains vmcnt: all h-stores + glds reads done before arrive
        if (tid == 0)
            __hip_atomic_fetch_add(cnt, 1u, __ATOMIC_RELEASE, __HIP_MEMORY_SCOPE_AGENT);
    }

    // c_last
    const size_t oc = (size_t)T_STEPS * BHSZ + BHSZ + (size_t)(m0 + er) * HID + hbase + ec;
    out[oc]           = c0;
    out[oc + 8 * HID] = c1;
}

extern "C" void kernel_launch(void* const* d_in, const int* in_sizes, int n_in,
                              void* d_out, int out_size, void* d_ws, size_t ws_size,
                              hipStream_t stream) {
    // ws layout: [0,256) barrier counter; [1024, 1024 + 2*B*H*2) bf16 h ping-pong
    hipMemsetAsync(d_ws, 0, 256, stream);
    unsigned* cnt  = (unsigned*)d_ws;
    short*   hping = (short*)((char*)d_ws + 1024);
    lstm_persistent<<<NBLK, 128, 0, stream>>>(
        (const float*)d_in[0],
        (const float*)d_in[1], (const float*)d_in[2],
        (const float*)d_in[3], (const float*)d_in[4],
        (const float*)d_in[5], (const float*)d_in[6],
        (const float*)d_in[7], (const float*)d_in[8],
        (float*)d_out, cnt, hping);
}